// Round 1
// baseline (651.232 us; speedup 1.0000x reference)
//
#include <hip/hip_runtime.h>

// MHFSpectralConv: rfft(16384)->256 modes->per-head complex mix->irfft + k3 conv, gated blend.
// Strategy: truncated DFT and sparse-spectrum synthesis as bf16 MFMA GEMMs against
// generated trig matrices; conv as 3 shifted GEMMs; all fp32 accumulate.

typedef __bf16 bf16x8 __attribute__((ext_vector_type(8)));
typedef float f32x4 __attribute__((ext_vector_type(4)));
typedef unsigned short ushort8v __attribute__((ext_vector_type(8)));

#define PI2_OVER_L 3.8349519697141029073e-4f  // 2*pi/16384

// ---------------- trig matrix generators ----------------
// Fjt[j][t], j=2k -> cos(2pi k t/L)/L ; j=2k+1 -> -sin(2pi k t/L)/L. Layout [512][16384].
__global__ void genF_kern(__bf16* __restrict__ Fjt) {
    unsigned idx = blockIdx.x * 256u + threadIdx.x;   // 256k x 16384t = 4194304
    unsigned k = idx >> 14, t = idx & 16383u;
    unsigned m = (k * t) & 16383u;                    // exact mod-L phase
    float th = (float)m * PI2_OVER_L;
    float s, c;
    __sincosf(th, &s, &c);
    const float inv = 1.0f / 16384.0f;
    Fjt[((size_t)(2u * k) << 14) + t]      = (__bf16)(c * inv);
    Fjt[((size_t)(2u * k + 1u) << 14) + t] = (__bf16)(-s * inv);
}

// Gtj[t][j], j=2k -> a_k cos ; j=2k+1 -> -a_k sin ; a_0=1 else 2. Layout [16384][512].
__global__ void genG_kern(__bf16* __restrict__ Gtj) {
    unsigned idx = blockIdx.x * 256u + threadIdx.x;   // 16384t x 256k
    unsigned t = idx >> 8, k = idx & 255u;
    unsigned m = (k * t) & 16383u;
    float th = (float)m * PI2_OVER_L;
    float s, c;
    __sincosf(th, &s, &c);
    float a = (k == 0u) ? 1.0f : 2.0f;
    size_t base = ((size_t)t << 9) + 2u * k;
    Gtj[base]     = (__bf16)(a * c);
    Gtj[base + 1] = (__bf16)(-a * s);
}

// conv_w (co,ci,3) fp32 -> wbf[d][co][ci] bf16
__global__ void wcvt_kern(const float* __restrict__ cw, __bf16* __restrict__ wbf) {
    int idx = blockIdx.x * 256 + threadIdx.x;         // 49152
    int co = idx / 384, r = idx - co * 384, ci = r / 3, d = r - ci * 3;
    wbf[d * 16384 + co * 128 + ci] = (__bf16)cw[idx];
}

// ---------------- forward GEMM: C1 = x @ F (split-K) ----------------
#define SA 72   // LDS row stride (elems): 144B = 9*16B, bank-shift 4
__global__ __launch_bounds__(256) void fwd_kern(const float* __restrict__ x,
        const __bf16* __restrict__ Fjt, float* __restrict__ Cp, int kchunk) {
    __shared__ __align__(16) __bf16 As[128 * SA];
    __shared__ __align__(16) __bf16 Bs[128 * SA];
    int bid = blockIdx.x;
    int mt = bid & 15, nt = (bid >> 4) & 3, ks = bid >> 6;
    int tid = threadIdx.x, lane = tid & 63, wv = tid >> 6;
    int wm = (wv >> 1) << 6, wn = (wv & 1) << 6;
    f32x4 acc[4][4] = {};
    int arow = tid >> 1, ahalf = (tid & 1) << 5;
    const float*  ag = x   + ((size_t)(mt * 128 + arow) << 14) + ahalf;
    const __bf16* bg = Fjt + ((size_t)(nt * 128 + arow) << 14) + ahalf;
    __bf16* ad = &As[arow * SA + ahalf];
    __bf16* bd = &Bs[arow * SA + ahalf];
    int k0 = ks * kchunk;
    for (int kk = 0; kk < kchunk; kk += 64) {
        const float4* ap = (const float4*)(ag + k0 + kk);
#pragma unroll
        for (int q = 0; q < 8; q++) {               // 32 fp32 -> bf16 into As
            float4 v = ap[q];
            ad[q * 4 + 0] = (__bf16)v.x; ad[q * 4 + 1] = (__bf16)v.y;
            ad[q * 4 + 2] = (__bf16)v.z; ad[q * 4 + 3] = (__bf16)v.w;
        }
        const ushort8v* bp = (const ushort8v*)(bg + k0 + kk);
#pragma unroll
        for (int q = 0; q < 4; q++) ((ushort8v*)bd)[q] = bp[q];
        __syncthreads();
#pragma unroll
        for (int ks2 = 0; ks2 < 64; ks2 += 32) {
            int kf = ks2 + ((lane >> 4) << 3);
            bf16x8 af[4], bfv[4];
#pragma unroll
            for (int i = 0; i < 4; i++)
                af[i] = *(const bf16x8*)&As[(wm + i * 16 + (lane & 15)) * SA + kf];
#pragma unroll
            for (int j = 0; j < 4; j++)
                bfv[j] = *(const bf16x8*)&Bs[(wn + j * 16 + (lane & 15)) * SA + kf];
#pragma unroll
            for (int i = 0; i < 4; i++)
#pragma unroll
                for (int j = 0; j < 4; j++)
                    acc[i][j] = __builtin_amdgcn_mfma_f32_16x16x32_bf16(af[i], bfv[j], acc[i][j], 0, 0, 0);
        }
        __syncthreads();
    }
    float* outp = Cp + (size_t)ks * (2048 * 512);
    int q = lane >> 4, cl = lane & 15;
#pragma unroll
    for (int i = 0; i < 4; i++)
#pragma unroll
        for (int j = 0; j < 4; j++) {
            int col = nt * 128 + wn + j * 16 + cl;
#pragma unroll
            for (int r = 0; r < 4; r++) {
                int row = mt * 128 + wm + i * 16 + q * 4 + r;
                outp[(size_t)row * 512 + col] = acc[i][j][r];
            }
        }
}

// ---------------- mixing: O = sum_i F * w (complex), a_k folded into G ----------------
__global__ __launch_bounds__(256) void mix_kern(const float* __restrict__ Cp,
        const float* __restrict__ wre, const float* __restrict__ wim,
        __bf16* __restrict__ Ob, int ns) {
    __shared__ float Fs[16 * 512];
    int bh = blockIdx.x, b = bh >> 3, h = bh & 7;
    int tid = threadIdx.x;
    size_t base = (size_t)(b * 128 + h * 16) * 512;   // 16 consecutive rows of 512
    for (int idx = tid; idx < 8192; idx += 256) {
        float v = 0.f;
        for (int s = 0; s < ns; s++) v += Cp[(size_t)s * 1048576 + base + idx];
        Fs[idx] = v;
    }
    __syncthreads();
    for (int idx = tid; idx < 4096; idx += 256) {
        int o = idx >> 8, k = idx & 255;
        float ar = 0.f, ai = 0.f;
        const float* wr0 = wre + ((size_t)(h * 256 + o) << 8) + k;
        const float* wi0 = wim + ((size_t)(h * 256 + o) << 8) + k;
#pragma unroll 4
        for (int i = 0; i < 16; i++) {
            float fr = Fs[i * 512 + 2 * k], fi = Fs[i * 512 + 2 * k + 1];
            float wr = wr0[(size_t)i * 4096], wi = wi0[(size_t)i * 4096];
            ar += fr * wr - fi * wi;
            ai += fr * wi + fi * wr;
        }
        size_t ro = (size_t)(b * 128 + h * 16 + o) * 512;
        Ob[ro + 2 * k]     = (__bf16)ar;
        Ob[ro + 2 * k + 1] = (__bf16)ai;
    }
}

// ---------------- conv branch: 3 shifted GEMMs, writes local (+conv_b) to out ----------------
#define SXC 40  // 80B rows = 5*16B
__global__ __launch_bounds__(256) void conv_kern(const float* __restrict__ x,
        const __bf16* __restrict__ wbf, const float* __restrict__ cb,
        float* __restrict__ out) {
    __shared__ __align__(16) __bf16 xT[130 * SXC];        // [t_local][ci_chunk]
    __shared__ __align__(16) __bf16 wS[3 * 128 * SXC];    // [d][co][ci_chunk]
    int bid = blockIdx.x, b = bid >> 7, t0 = (bid & 127) << 7;
    int tid = threadIdx.x, lane = tid & 63, wv = tid >> 6;
    int wm = (wv >> 1) << 6, wn = (wv & 1) << 6;
    f32x4 acc[4][4] = {};
    for (int c0 = 0; c0 < 128; c0 += 32) {
        for (int idx = tid; idx < 1536; idx += 256) {     // w chunk: 3*128*32 bf16 as vec8
            int d = idx / 512, rem = idx - d * 512, co = rem >> 2, g = rem & 3;
            ushort8v v = *(const ushort8v*)(wbf + d * 16384 + co * 128 + c0 + g * 8);
            *(ushort8v*)&wS[d * (128 * SXC) + co * SXC + g * 8] = v;
        }
        for (int idx = tid; idx < 4160; idx += 256) {     // x chunk: 32ci x 130t, transpose+pad
            int cc = idx / 130, tl = idx - cc * 130;
            int tg = t0 + tl - 1;
            float v = 0.f;
            if (tg >= 0 && tg < 16384)
                v = x[((size_t)(b * 128 + c0 + cc) << 14) + tg];
            xT[tl * SXC + cc] = (__bf16)v;
        }
        __syncthreads();
        int kf = (lane >> 4) << 3;
#pragma unroll
        for (int d = 0; d < 3; d++) {
            bf16x8 af[4], bfv[4];
#pragma unroll
            for (int i = 0; i < 4; i++)
                af[i] = *(const bf16x8*)&wS[d * (128 * SXC) + (wm + i * 16 + (lane & 15)) * SXC + kf];
#pragma unroll
            for (int j = 0; j < 4; j++)
                bfv[j] = *(const bf16x8*)&xT[(wn + j * 16 + (lane & 15) + d) * SXC + kf];
#pragma unroll
            for (int i = 0; i < 4; i++)
#pragma unroll
                for (int j = 0; j < 4; j++)
                    acc[i][j] = __builtin_amdgcn_mfma_f32_16x16x32_bf16(af[i], bfv[j], acc[i][j], 0, 0, 0);
        }
        __syncthreads();
    }
    int q = lane >> 4, cl = lane & 15;
#pragma unroll
    for (int i = 0; i < 4; i++)
#pragma unroll
        for (int j = 0; j < 4; j++) {
            int t = t0 + wn + j * 16 + cl;
#pragma unroll
            for (int r = 0; r < 4; r++) {
                int co = wm + i * 16 + q * 4 + r;
                out[((size_t)(b * 128 + co) << 14) + t] = acc[i][j][r] + cb[co];
            }
        }
}

// ---------------- inverse GEMM: spec = O' @ G, fused gate/bias/local epilogue ----------------
__global__ __launch_bounds__(256) void inv_kern(const __bf16* __restrict__ Ob,
        const __bf16* __restrict__ Gtj, const float* __restrict__ bias,
        const float* __restrict__ gate, float* __restrict__ out) {
    __shared__ __align__(16) __bf16 As[128 * SA];
    __shared__ __align__(16) __bf16 Bs[128 * SA];
    int bid = blockIdx.x, mt = bid & 15, tt = bid >> 4;
    int tid = threadIdx.x, lane = tid & 63, wv = tid >> 6;
    int wm = (wv >> 1) << 6, wn = (wv & 1) << 6;
    f32x4 acc[4][4] = {};
    int arow = tid >> 1, ahalf = (tid & 1) << 5;
    const __bf16* ag = Ob  + (size_t)(mt * 128 + arow) * 512 + ahalf;
    const __bf16* bg = Gtj + (size_t)(tt * 128 + arow) * 512 + ahalf;
    __bf16* ad = &As[arow * SA + ahalf];
    __bf16* bd = &Bs[arow * SA + ahalf];
    for (int k0 = 0; k0 < 512; k0 += 64) {
#pragma unroll
        for (int q = 0; q < 4; q++) {
            ((ushort8v*)ad)[q] = ((const ushort8v*)(ag + k0))[q];
            ((ushort8v*)bd)[q] = ((const ushort8v*)(bg + k0))[q];
        }
        __syncthreads();
#pragma unroll
        for (int ks2 = 0; ks2 < 64; ks2 += 32) {
            int kf = ks2 + ((lane >> 4) << 3);
            bf16x8 af[4], bfv[4];
#pragma unroll
            for (int i = 0; i < 4; i++)
                af[i] = *(const bf16x8*)&As[(wm + i * 16 + (lane & 15)) * SA + kf];
#pragma unroll
            for (int j = 0; j < 4; j++)
                bfv[j] = *(const bf16x8*)&Bs[(wn + j * 16 + (lane & 15)) * SA + kf];
#pragma unroll
            for (int i = 0; i < 4; i++)
#pragma unroll
                for (int j = 0; j < 4; j++)
                    acc[i][j] = __builtin_amdgcn_mfma_f32_16x16x32_bf16(af[i], bfv[j], acc[i][j], 0, 0, 0);
        }
        __syncthreads();
    }
    float g = 1.0f / (1.0f + __expf(-gate[0]));
    float gi = 1.0f - g;
    int q = lane >> 4, cl = lane & 15;
#pragma unroll
    for (int i = 0; i < 4; i++)
#pragma unroll
        for (int j = 0; j < 4; j++) {
            int col = (tt << 7) + wn + j * 16 + cl;
#pragma unroll
            for (int r = 0; r < 4; r++) {
                int row = mt * 128 + wm + i * 16 + q * 4 + r;
                size_t oi = ((size_t)row << 14) + col;
                out[oi] = g * (acc[i][j][r] + bias[row & 127]) + gi * out[oi];
            }
        }
}

extern "C" void kernel_launch(void* const* d_in, const int* in_sizes, int n_in,
                              void* d_out, int out_size, void* d_ws, size_t ws_size,
                              hipStream_t stream) {
    const float* x    = (const float*)d_in[0];
    const float* wre  = (const float*)d_in[1];
    const float* wim  = (const float*)d_in[2];
    const float* bias = (const float*)d_in[3];
    const float* cw   = (const float*)d_in[4];
    const float* cb   = (const float*)d_in[5];
    const float* gate = (const float*)d_in[6];
    float* out = (float*)d_out;
    char* ws = (char*)d_ws;

    __bf16* Fjt = (__bf16*)(ws);                      // 16,777,216 B
    __bf16* Gtj = (__bf16*)(ws + 16777216);           // 16,777,216 B
    __bf16* wbf = (__bf16*)(ws + 33554432);           //     98,304 B
    float*  Cp  = (float*)(ws + 33652736);            // ns * 4,194,304 B
    size_t need8 = 33652736ull + 8ull * 4194304ull + 2097152ull;
    int ns = (ws_size >= need8) ? 8 : 4;              // split-K factor for forward GEMM
    __bf16* Ob  = (__bf16*)(ws + 33652736 + (size_t)ns * 4194304);
    int kchunk = 16384 / ns;

    genF_kern<<<16384, 256, 0, stream>>>(Fjt);
    genG_kern<<<16384, 256, 0, stream>>>(Gtj);
    wcvt_kern<<<192, 256, 0, stream>>>(cw, wbf);
    fwd_kern<<<64 * ns, 256, 0, stream>>>(x, Fjt, Cp, kchunk);
    mix_kern<<<128, 256, 0, stream>>>(Cp, wre, wim, Ob, ns);
    conv_kern<<<2048, 256, 0, stream>>>(x, wbf, cb, out);
    inv_kern<<<2048, 256, 0, stream>>>(Ob, Gtj, bias, gate, out);
}

// Round 2
// 520.712 us; speedup vs baseline: 1.2507x; 1.2507x over previous
//
#include <hip/hip_runtime.h>

// MHFSpectralConv: rfft(16384)->256 modes->per-head complex mix->irfft + k3 conv, gated blend.
// R2: pre-transposed bf16 x (xTb [b][t][ci]); conv fused into inverse GEMM with g/(1-g)
// folded into G / W so out is write-only; fwd reads bf16 xb; mix split to 256 blocks.

typedef __bf16 bf16x8 __attribute__((ext_vector_type(8)));
typedef __bf16 bf16x4 __attribute__((ext_vector_type(4)));
typedef float f32x4 __attribute__((ext_vector_type(4)));
typedef unsigned short ushort8v __attribute__((ext_vector_type(8)));

#define PI2_OVER_L 3.8349519697141029073e-4f  // 2*pi/16384

// ---------------- trig matrix generators ----------------
// Fjt[j][t], j=2k -> cos/L ; j=2k+1 -> -sin/L. Layout [512][16384].
__global__ void genF_kern(__bf16* __restrict__ Fjt) {
    unsigned idx = blockIdx.x * 256u + threadIdx.x;
    unsigned k = idx >> 14, t = idx & 16383u;
    unsigned m = (k * t) & 16383u;
    float th = (float)m * PI2_OVER_L;
    float s, c;
    __sincosf(th, &s, &c);
    const float inv = 1.0f / 16384.0f;
    Fjt[((size_t)(2u * k) << 14) + t]      = (__bf16)(c * inv);
    Fjt[((size_t)(2u * k + 1u) << 14) + t] = (__bf16)(-s * inv);
}

// Gtj[t][j]: j=2k -> a_k cos ; j=2k+1 -> -a_k sin ; a_0=1 else 2. fold: *g (sigmoid(gate)).
__global__ void genG_kern(__bf16* __restrict__ Gtj, const float* __restrict__ gate, int fold) {
    unsigned idx = blockIdx.x * 256u + threadIdx.x;
    unsigned t = idx >> 8, k = idx & 255u;
    unsigned m = (k * t) & 16383u;
    float th = (float)m * PI2_OVER_L;
    float s, c;
    __sincosf(th, &s, &c);
    float a = (k == 0u) ? 1.0f : 2.0f;
    if (fold) a *= 1.0f / (1.0f + __expf(-gate[0]));
    size_t base = ((size_t)t << 9) + 2u * k;
    Gtj[base]     = (__bf16)(a * c);
    Gtj[base + 1] = (__bf16)(-a * s);
}

// conv_w (co,ci,3) fp32 -> wbf[d][co][ci] bf16. fold: *(1-g).
__global__ void wcvt_kern(const float* __restrict__ cw, __bf16* __restrict__ wbf,
                          const float* __restrict__ gate, int fold) {
    int idx = blockIdx.x * 256 + threadIdx.x;         // 49152
    float sc = 1.0f;
    if (fold) sc = 1.0f - 1.0f / (1.0f + __expf(-gate[0]));
    int co = idx / 384, r = idx - co * 384, ci = r / 3, d = r - ci * 3;
    wbf[d * 16384 + co * 128 + ci] = (__bf16)(cw[idx] * sc);
}

// ---------------- transpose: x fp32 [b][ci][t] -> xTb bf16 [b][t][ci] (+ xb bf16 [b][ci][t]) ----
__global__ __launch_bounds__(256) void xpose_kern(const float* __restrict__ x,
        __bf16* __restrict__ xb, __bf16* __restrict__ xTb, int write_xb) {
    __shared__ __bf16 tile[128 * 68];                 // [ci][t], stride 68 (+8B pad)
    int bid = blockIdx.x;                             // 16 b x 256 tB
    int b = bid >> 8, tB = bid & 255, t0 = tB << 6;
    int tid = threadIdx.x;
    for (int idx = tid; idx < 2048; idx += 256) {     // 128 ci x 16 float4
        int ci = idx >> 4, ch = idx & 15;
        size_t gp = ((size_t)((b << 7) + ci) << 14) + t0 + (ch << 2);
        float4 v = *(const float4*)(x + gp);
        bf16x4 p;
        p[0] = (__bf16)v.x; p[1] = (__bf16)v.y; p[2] = (__bf16)v.z; p[3] = (__bf16)v.w;
        *(bf16x4*)&tile[ci * 68 + (ch << 2)] = p;
        if (write_xb) *(bf16x4*)(xb + gp) = p;
    }
    __syncthreads();
    for (int idx = tid; idx < 1024; idx += 256) {     // 64 t x 16 ci-chunks
        int t = idx >> 4, ch = idx & 15;
        bf16x8 v;
#pragma unroll
        for (int j = 0; j < 8; j++) v[j] = tile[(ch * 8 + j) * 68 + t];
        *(bf16x8*)(xTb + (((size_t)(b << 14)) + t0 + t) * 128 + ch * 8) = v;
    }
}

// ---------------- forward GEMM: C1 = x @ F (split-K) ----------------
#define SA 72   // LDS row stride (elems): 144B
template<int ABF>
__global__ __launch_bounds__(256) void fwd_kern(const float* __restrict__ xf,
        const __bf16* __restrict__ xbv, const __bf16* __restrict__ Fjt,
        float* __restrict__ Cp, int kchunk) {
    __shared__ __align__(16) __bf16 As[128 * SA];
    __shared__ __align__(16) __bf16 Bs[128 * SA];
    int bid = blockIdx.x;
    int mt = bid & 15, nt = (bid >> 4) & 3, ks = bid >> 6;
    int tid = threadIdx.x, lane = tid & 63, wv = tid >> 6;
    int wm = (wv >> 1) << 6, wn = (wv & 1) << 6;
    f32x4 acc[4][4] = {};
    int arow = tid >> 1, ahalf = (tid & 1) << 5;
    const float*  agf = xf  + ((size_t)(mt * 128 + arow) << 14) + ahalf;
    const __bf16* agb = xbv + ((size_t)(mt * 128 + arow) << 14) + ahalf;
    const __bf16* bg  = Fjt + ((size_t)(nt * 128 + arow) << 14) + ahalf;
    __bf16* ad = &As[arow * SA + ahalf];
    __bf16* bd = &Bs[arow * SA + ahalf];
    int k0 = ks * kchunk;
    for (int kk = 0; kk < kchunk; kk += 64) {
        if (ABF) {
            const ushort8v* ap = (const ushort8v*)(agb + k0 + kk);
#pragma unroll
            for (int q = 0; q < 4; q++) ((ushort8v*)ad)[q] = ap[q];
        } else {
            const float4* ap = (const float4*)(agf + k0 + kk);
#pragma unroll
            for (int q = 0; q < 8; q++) {
                float4 v = ap[q];
                ad[q * 4 + 0] = (__bf16)v.x; ad[q * 4 + 1] = (__bf16)v.y;
                ad[q * 4 + 2] = (__bf16)v.z; ad[q * 4 + 3] = (__bf16)v.w;
            }
        }
        const ushort8v* bp = (const ushort8v*)(bg + k0 + kk);
#pragma unroll
        for (int q = 0; q < 4; q++) ((ushort8v*)bd)[q] = bp[q];
        __syncthreads();
#pragma unroll
        for (int ks2 = 0; ks2 < 64; ks2 += 32) {
            int kf = ks2 + ((lane >> 4) << 3);
            bf16x8 af[4], bfv[4];
#pragma unroll
            for (int i = 0; i < 4; i++)
                af[i] = *(const bf16x8*)&As[(wm + i * 16 + (lane & 15)) * SA + kf];
#pragma unroll
            for (int j = 0; j < 4; j++)
                bfv[j] = *(const bf16x8*)&Bs[(wn + j * 16 + (lane & 15)) * SA + kf];
#pragma unroll
            for (int i = 0; i < 4; i++)
#pragma unroll
                for (int j = 0; j < 4; j++)
                    acc[i][j] = __builtin_amdgcn_mfma_f32_16x16x32_bf16(af[i], bfv[j], acc[i][j], 0, 0, 0);
        }
        __syncthreads();
    }
    float* outp = Cp + (size_t)ks * (2048 * 512);
    int q = lane >> 4, cl = lane & 15;
#pragma unroll
    for (int i = 0; i < 4; i++)
#pragma unroll
        for (int j = 0; j < 4; j++) {
            int col = nt * 128 + wn + j * 16 + cl;
#pragma unroll
            for (int r = 0; r < 4; r++) {
                int row = mt * 128 + wm + i * 16 + q * 4 + r;
                outp[(size_t)row * 512 + col] = acc[i][j][r];
            }
        }
}

// ---------------- mixing: O = sum_i F * w (complex). grid 256 = 128 bh x 2 k-halves ---------
__global__ __launch_bounds__(256) void mix_kern(const float* __restrict__ Cp,
        const float* __restrict__ wre, const float* __restrict__ wim,
        __bf16* __restrict__ Ob, int ns) {
    __shared__ float Fs[16 * 256];
    int bid = blockIdx.x, bh = bid >> 1, kh = bid & 1;
    int b = bh >> 3, h = bh & 7;
    int tid = threadIdx.x;
    size_t base = (size_t)(b * 128 + h * 16) * 512 + kh * 256;
    for (int idx = tid; idx < 4096; idx += 256) {
        int i = idx >> 8, jj = idx & 255;
        float v = 0.f;
        for (int s = 0; s < ns; s++) v += Cp[(size_t)s * 1048576 + base + (size_t)i * 512 + jj];
        Fs[i * 256 + jj] = v;
    }
    __syncthreads();
    for (int idx = tid; idx < 2048; idx += 256) {
        int o = idx >> 7, kl = idx & 127;
        int k = kh * 128 + kl;
        float ar = 0.f, ai = 0.f;
        const float* wr0 = wre + ((size_t)(h * 256 + o) << 8) + k;
        const float* wi0 = wim + ((size_t)(h * 256 + o) << 8) + k;
#pragma unroll 4
        for (int i = 0; i < 16; i++) {
            float fr = Fs[i * 256 + 2 * kl], fi = Fs[i * 256 + 2 * kl + 1];
            float wr = wr0[(size_t)i * 4096], wi = wi0[(size_t)i * 4096];
            ar += fr * wr - fi * wi;
            ai += fr * wi + fi * wr;
        }
        size_t ro = (size_t)(b * 128 + h * 16 + o) * 512;
        Ob[ro + 2 * k]     = (__bf16)ar;
        Ob[ro + 2 * k + 1] = (__bf16)ai;
    }
}

// ---------------- fused inverse + conv: out = Ob@(g*G) + ((1-g)*W)*xT + blended bias --------
#define SC 72   // conv LDS row stride for 64-wide ci chunks
__global__ __launch_bounds__(256) void fused_kern(const __bf16* __restrict__ Ob,
        const __bf16* __restrict__ Gtj, const __bf16* __restrict__ wbf,
        const __bf16* __restrict__ xTb, const float* __restrict__ bias,
        const float* __restrict__ cb, const float* __restrict__ gate,
        float* __restrict__ out) {
    __shared__ __align__(16) char smem[37152];
    int bid = blockIdx.x, b = bid & 15, tt = bid >> 4;   // 16 b x 128 t-tiles
    int t0 = tt << 7;
    int tid = threadIdx.x, lane = tid & 63, wv = tid >> 6;
    int wm = (wv >> 1) << 6, wn = (wv & 1) << 6, lm = lane & 15;
    f32x4 acc[4][4] = {};

    // ---- spectral phase: K=512 over Ob rows (m=co) x Gtj rows (n=t) ----
    {
        __bf16* As = (__bf16*)smem;                   // 128 x SA
        __bf16* Bs = (__bf16*)(smem + 128 * SA * 2);  // 128 x SA
        int arow = tid >> 1, ahalf = (tid & 1) << 5;
        const __bf16* ag = Ob  + (size_t)(b * 128 + arow) * 512 + ahalf;
        const __bf16* bg = Gtj + (size_t)(tt * 128 + arow) * 512 + ahalf;
        __bf16* ad = &As[arow * SA + ahalf];
        __bf16* bd = &Bs[arow * SA + ahalf];
        for (int k0 = 0; k0 < 512; k0 += 64) {
#pragma unroll
            for (int q = 0; q < 4; q++) {
                ((ushort8v*)ad)[q] = ((const ushort8v*)(ag + k0))[q];
                ((ushort8v*)bd)[q] = ((const ushort8v*)(bg + k0))[q];
            }
            __syncthreads();
#pragma unroll
            for (int ks2 = 0; ks2 < 64; ks2 += 32) {
                int kf = ks2 + ((lane >> 4) << 3);
                bf16x8 af[4], bfv[4];
#pragma unroll
                for (int i = 0; i < 4; i++)
                    af[i] = *(const bf16x8*)&As[(wm + i * 16 + lm) * SA + kf];
#pragma unroll
                for (int j = 0; j < 4; j++)
                    bfv[j] = *(const bf16x8*)&Bs[(wn + j * 16 + lm) * SA + kf];
#pragma unroll
                for (int i = 0; i < 4; i++)
#pragma unroll
                    for (int j = 0; j < 4; j++)
                        acc[i][j] = __builtin_amdgcn_mfma_f32_16x16x32_bf16(af[i], bfv[j], acc[i][j], 0, 0, 0);
            }
            __syncthreads();
        }
    }

    // ---- conv phase: K = 3 taps x 128 ci (ci chunked by 64) ----
    {
        __bf16* xT = (__bf16*)smem;                   // 130 x SC
        __bf16* Ws = (__bf16*)(smem + 130 * SC * 2);  // 128 x SC
        for (int c0p = 0; c0p < 2; c0p++) {
            int c0 = c0p << 6;
            if (c0p) __syncthreads();                 // prior MFMA done before xT overwrite
            for (int idx = tid; idx < 1040; idx += 256) {   // 130 rows x 8 chunks
                int row = idx >> 3, ch = idx & 7;
                int tg = t0 - 1 + row;
                ushort8v v = {};
                if (tg >= 0 && tg < 16384)
                    v = *(const ushort8v*)(xTb + (((size_t)(b << 14)) + tg) * 128 + c0 + ch * 8);
                *(ushort8v*)&xT[row * SC + ch * 8] = v;
            }
            for (int d = 0; d < 3; d++) {
                if (d) __syncthreads();               // prior MFMA done before Ws overwrite
                for (int idx = tid; idx < 1024; idx += 256) {  // 128 co x 8 chunks
                    int co = idx >> 3, ch = idx & 7;
                    *(ushort8v*)&Ws[co * SC + ch * 8] =
                        *(const ushort8v*)(wbf + d * 16384 + co * 128 + c0 + ch * 8);
                }
                __syncthreads();
#pragma unroll
                for (int ks2 = 0; ks2 < 64; ks2 += 32) {
                    int kf = ks2 + ((lane >> 4) << 3);
                    bf16x8 af[4], bfv[4];
#pragma unroll
                    for (int i = 0; i < 4; i++)
                        af[i] = *(const bf16x8*)&Ws[(wm + i * 16 + lm) * SC + kf];
#pragma unroll
                    for (int j = 0; j < 4; j++)
                        bfv[j] = *(const bf16x8*)&xT[(wn + j * 16 + lm + d) * SC + kf];
#pragma unroll
                    for (int i = 0; i < 4; i++)
#pragma unroll
                        for (int j = 0; j < 4; j++)
                            acc[i][j] = __builtin_amdgcn_mfma_f32_16x16x32_bf16(af[i], bfv[j], acc[i][j], 0, 0, 0);
                }
            }
        }
    }

    // ---- epilogue: blended bias, write-only out ----
    float g = 1.0f / (1.0f + __expf(-gate[0]));
    int q = lane >> 4, cl = lane & 15;
#pragma unroll
    for (int i = 0; i < 4; i++)
#pragma unroll
        for (int j = 0; j < 4; j++) {
            int t = t0 + wn + j * 16 + cl;
#pragma unroll
            for (int r = 0; r < 4; r++) {
                int co = wm + i * 16 + q * 4 + r;
                float gb = g * bias[co] + (1.0f - g) * cb[co];
                out[((size_t)(b * 128 + co) << 14) + t] = acc[i][j][r] + gb;
            }
        }
}

// ---------------- fallback (low-ws) conv + inv, round-1 versions ----------------
#define SXC 40
__global__ __launch_bounds__(256) void conv_kern(const float* __restrict__ x,
        const __bf16* __restrict__ wbf, const float* __restrict__ cb,
        float* __restrict__ out) {
    __shared__ __align__(16) __bf16 xT[130 * SXC];
    __shared__ __align__(16) __bf16 wS[3 * 128 * SXC];
    int bid = blockIdx.x, b = bid >> 7, t0 = (bid & 127) << 7;
    int tid = threadIdx.x, lane = tid & 63, wv = tid >> 6;
    int wm = (wv >> 1) << 6, wn = (wv & 1) << 6;
    f32x4 acc[4][4] = {};
    for (int c0 = 0; c0 < 128; c0 += 32) {
        for (int idx = tid; idx < 1536; idx += 256) {
            int d = idx / 512, rem = idx - d * 512, co = rem >> 2, g = rem & 3;
            ushort8v v = *(const ushort8v*)(wbf + d * 16384 + co * 128 + c0 + g * 8);
            *(ushort8v*)&wS[d * (128 * SXC) + co * SXC + g * 8] = v;
        }
        for (int idx = tid; idx < 4160; idx += 256) {
            int cc = idx / 130, tl = idx - cc * 130;
            int tg = t0 + tl - 1;
            float v = 0.f;
            if (tg >= 0 && tg < 16384)
                v = x[((size_t)(b * 128 + c0 + cc) << 14) + tg];
            xT[tl * SXC + cc] = (__bf16)v;
        }
        __syncthreads();
        int kf = (lane >> 4) << 3;
#pragma unroll
        for (int d = 0; d < 3; d++) {
            bf16x8 af[4], bfv[4];
#pragma unroll
            for (int i = 0; i < 4; i++)
                af[i] = *(const bf16x8*)&wS[d * (128 * SXC) + (wm + i * 16 + (lane & 15)) * SXC + kf];
#pragma unroll
            for (int j = 0; j < 4; j++)
                bfv[j] = *(const bf16x8*)&xT[(wn + j * 16 + (lane & 15) + d) * SXC + kf];
#pragma unroll
            for (int i = 0; i < 4; i++)
#pragma unroll
                for (int j = 0; j < 4; j++)
                    acc[i][j] = __builtin_amdgcn_mfma_f32_16x16x32_bf16(af[i], bfv[j], acc[i][j], 0, 0, 0);
        }
        __syncthreads();
    }
    int q = lane >> 4, cl = lane & 15;
#pragma unroll
    for (int i = 0; i < 4; i++)
#pragma unroll
        for (int j = 0; j < 4; j++) {
            int t = t0 + wn + j * 16 + cl;
#pragma unroll
            for (int r = 0; r < 4; r++) {
                int co = wm + i * 16 + q * 4 + r;
                out[((size_t)(b * 128 + co) << 14) + t] = acc[i][j][r] + cb[co];
            }
        }
}

__global__ __launch_bounds__(256) void inv_kern(const __bf16* __restrict__ Ob,
        const __bf16* __restrict__ Gtj, const float* __restrict__ bias,
        const float* __restrict__ gate, float* __restrict__ out) {
    __shared__ __align__(16) __bf16 As[128 * SA];
    __shared__ __align__(16) __bf16 Bs[128 * SA];
    int bid = blockIdx.x, mt = bid & 15, tt = bid >> 4;
    int tid = threadIdx.x, lane = tid & 63, wv = tid >> 6;
    int wm = (wv >> 1) << 6, wn = (wv & 1) << 6;
    f32x4 acc[4][4] = {};
    int arow = tid >> 1, ahalf = (tid & 1) << 5;
    const __bf16* ag = Ob  + (size_t)(mt * 128 + arow) * 512 + ahalf;
    const __bf16* bg = Gtj + (size_t)(tt * 128 + arow) * 512 + ahalf;
    __bf16* ad = &As[arow * SA + ahalf];
    __bf16* bd = &Bs[arow * SA + ahalf];
    for (int k0 = 0; k0 < 512; k0 += 64) {
#pragma unroll
        for (int q = 0; q < 4; q++) {
            ((ushort8v*)ad)[q] = ((const ushort8v*)(ag + k0))[q];
            ((ushort8v*)bd)[q] = ((const ushort8v*)(bg + k0))[q];
        }
        __syncthreads();
#pragma unroll
        for (int ks2 = 0; ks2 < 64; ks2 += 32) {
            int kf = ks2 + ((lane >> 4) << 3);
            bf16x8 af[4], bfv[4];
#pragma unroll
            for (int i = 0; i < 4; i++)
                af[i] = *(const bf16x8*)&As[(wm + i * 16 + (lane & 15)) * SA + kf];
#pragma unroll
            for (int j = 0; j < 4; j++)
                bfv[j] = *(const bf16x8*)&Bs[(wn + j * 16 + (lane & 15)) * SA + kf];
#pragma unroll
            for (int i = 0; i < 4; i++)
#pragma unroll
                for (int j = 0; j < 4; j++)
                    acc[i][j] = __builtin_amdgcn_mfma_f32_16x16x32_bf16(af[i], bfv[j], acc[i][j], 0, 0, 0);
        }
        __syncthreads();
    }
    float g = 1.0f / (1.0f + __expf(-gate[0]));
    float gi = 1.0f - g;
    int q = lane >> 4, cl = lane & 15;
#pragma unroll
    for (int i = 0; i < 4; i++)
#pragma unroll
        for (int j = 0; j < 4; j++) {
            int col = (tt << 7) + wn + j * 16 + cl;
#pragma unroll
            for (int r = 0; r < 4; r++) {
                int row = mt * 128 + wm + i * 16 + q * 4 + r;
                size_t oi = ((size_t)row << 14) + col;
                out[oi] = g * (acc[i][j][r] + bias[row & 127]) + gi * out[oi];
            }
        }
}

extern "C" void kernel_launch(void* const* d_in, const int* in_sizes, int n_in,
                              void* d_out, int out_size, void* d_ws, size_t ws_size,
                              hipStream_t stream) {
    const float* x    = (const float*)d_in[0];
    const float* wre  = (const float*)d_in[1];
    const float* wim  = (const float*)d_in[2];
    const float* bias = (const float*)d_in[3];
    const float* cw   = (const float*)d_in[4];
    const float* cb   = (const float*)d_in[5];
    const float* gate = (const float*)d_in[6];
    float* out = (float*)d_out;
    char* ws = (char*)d_ws;

    const size_t SZ_F = 16777216, SZ_G = 16777216, SZ_W = 98304;
    const size_t SZ_X = 67108864, SZ_CP8 = 33554432, SZ_CP4 = 16777216, SZ_OB = 2097152;
    size_t oG = SZ_F, oW = oG + SZ_G, oEnd = oW + SZ_W;   // 33,652,736

    size_t needT3 = oEnd + 2 * SZ_X + SZ_CP8 + SZ_OB;     // 203,522,048
    size_t needT2 = oEnd + SZ_X + SZ_CP8 + SZ_OB;         // 136,413,184
    size_t needT1 = oEnd + SZ_X + SZ_CP4 + SZ_OB;         // 119,635,968

    __bf16* Fjt = (__bf16*)(ws);
    __bf16* Gtj = (__bf16*)(ws + oG);
    __bf16* wbf = (__bf16*)(ws + oW);

    if (ws_size >= needT1) {
        // fused path
        int use_xb = (ws_size >= needT3);
        int ns = (ws_size >= needT2) ? 8 : 4;
        __bf16* xb  = use_xb ? (__bf16*)(ws + oEnd) : nullptr;
        __bf16* xTb = (__bf16*)(ws + oEnd + (use_xb ? SZ_X : 0));
        float*  Cp  = (float*)((char*)xTb + SZ_X);
        __bf16* Ob  = (__bf16*)((char*)Cp + (size_t)ns * 4194304);
        int kchunk = 16384 / ns;

        genF_kern<<<16384, 256, 0, stream>>>(Fjt);
        genG_kern<<<16384, 256, 0, stream>>>(Gtj, gate, 1);
        wcvt_kern<<<192, 256, 0, stream>>>(cw, wbf, gate, 1);
        xpose_kern<<<4096, 256, 0, stream>>>(x, xb, xTb, use_xb);
        if (use_xb)
            fwd_kern<1><<<64 * ns, 256, 0, stream>>>(x, xb, Fjt, Cp, kchunk);
        else
            fwd_kern<0><<<64 * ns, 256, 0, stream>>>(x, nullptr, Fjt, Cp, kchunk);
        mix_kern<<<256, 256, 0, stream>>>(Cp, wre, wim, Ob, ns);
        fused_kern<<<2048, 256, 0, stream>>>(Ob, Gtj, wbf, xTb, bias, cb, gate, out);
    } else {
        // round-1 fallback path
        float*  Cp  = (float*)(ws + oEnd);
        size_t need8 = oEnd + 8ull * 4194304ull + SZ_OB;
        int ns = (ws_size >= need8) ? 8 : 4;
        __bf16* Ob  = (__bf16*)(ws + oEnd + (size_t)ns * 4194304);
        int kchunk = 16384 / ns;

        genF_kern<<<16384, 256, 0, stream>>>(Fjt);
        genG_kern<<<16384, 256, 0, stream>>>(Gtj, gate, 0);
        wcvt_kern<<<192, 256, 0, stream>>>(cw, wbf, gate, 0);
        fwd_kern<0><<<64 * ns, 256, 0, stream>>>(x, nullptr, Fjt, Cp, kchunk);
        mix_kern<<<256, 256, 0, stream>>>(Cp, wre, wim, Ob, ns);
        conv_kern<<<2048, 256, 0, stream>>>(x, wbf, cb, out);
        inv_kern<<<2048, 256, 0, stream>>>(Ob, Gtj, bias, gate, out);
    }
}